// Round 8
// baseline (437.467 us; speedup 1.0000x reference)
//
#include <hip/hip_runtime.h>

// GSSelfAttn: B=2048 windows, N=144 tokens, D=180, H=6 heads, hd=30.
// R8: W read DIRECTLY from L2 (fragment-packed, coalesced) -> no LDS W stage,
// no W double-buffer, 1 barrier/head (6 total, 0 in epilogue). K/Vt parity
// double-buffered in LDS. Vt scatter packed b64. Streaming no-max softmax
// (log2e pre-folded), swapped QK^T, O in registers. Spill-free.
// LDS 78336 B: strips 41472 | K0 9216 | K1 9216 | Vt0 9216 | Vt1 9216.

typedef __bf16 bf16_t;
typedef __bf16 bf16x8 __attribute__((ext_vector_type(8)));
typedef __bf16 bf16x4 __attribute__((ext_vector_type(4)));
typedef float f32x4 __attribute__((ext_vector_type(4)));

#define MFMA16(a, b, c) __builtin_amdgcn_mfma_f32_16x16x32_bf16((a), (b), (c), 0, 0, 0)

static __device__ __forceinline__ f32x4 fzero4() {
    f32x4 z; z[0] = 0.f; z[1] = 0.f; z[2] = 0.f; z[3] = 0.f; return z;
}
static __device__ __forceinline__ bf16x8 bzero8() {
    bf16x8 z;
    #pragma unroll
    for (int i = 0; i < 8; ++i) z[i] = (bf16_t)0.f;
    return z;
}

// ---------------- pack kernel ----------------
// ws layout (bytes):
//   Wqkv  @ 0      : [h][kt6][nt6][lane64][j8] bf16      = 221184 B  (Q cols pre-scaled by 30^-.5*log2e)
//   Wp    @ 221184 : [half2][kt6][ntl6][lane64][j8] bf16 =  73728 B  (half-major)
//   BIASf @ 294912 : [h][wv9][nt9][lane64][r4] bf16      = 248832 B  (S^T fragment layout, *log2e)
//   bqkv  @ 543744 : [h][c96]                 fp32       =   2304 B  (Q part *scale*log2e)
__global__ void pack_kernel(const float* __restrict__ wq, const float* __restrict__ bq,
                            const float* __restrict__ wk, const float* __restrict__ bk,
                            const float* __restrict__ wv, const float* __restrict__ bv,
                            const float* __restrict__ wp, const float* __restrict__ bt,
                            bf16_t* __restrict__ Wqkv, bf16_t* __restrict__ Wp,
                            bf16_t* __restrict__ BIASf, float* __restrict__ bqkv)
{
    const int t = blockIdx.x * blockDim.x + threadIdx.x;
    const int stride = gridDim.x * blockDim.x;
    const float L2E = 1.4426950408889634f;
    const float qscale = 0.18257418583505536f * L2E;   // 30^-0.5 * log2e, folded into Q

    for (int i = t; i < 6 * 6 * 6 * 512; i += stride) {
        int j = i & 7, lane = (i >> 3) & 63;
        int f = i >> 9;               // [h][kt][nt]
        int nt = f % 6, kt = (f / 6) % 6, h = f / 36;
        int kin = kt * 32 + (lane >> 4) * 8 + j;
        int c = nt * 16 + (lane & 15);       // 0..95
        int sec = c >> 5, d = c & 31;
        float v = 0.f;
        if (kin < 180 && d < 30) {
            int col = h * 30 + d;
            if (sec == 0)      v = wq[kin * 180 + col] * qscale;
            else if (sec == 1) v = wk[kin * 180 + col];
            else               v = wv[kin * 180 + col];
        }
        Wqkv[i] = (bf16_t)v;
    }
    for (int i = t; i < 2 * 6 * 6 * 512; i += stride) {
        int j = i & 7, lane = (i >> 3) & 63;
        int f = i >> 9;               // [half][kt][ntl]
        int ntl = f % 6, kt = (f / 6) % 6, half = f / 36;
        int nt = half * 6 + ntl;
        int kin = kt * 32 + (lane >> 4) * 8 + j;
        int hh = kin >> 5, d = kin & 31;
        int cout = nt * 16 + (lane & 15);
        float v = 0.f;
        if (d < 30 && cout < 180) v = wp[(hh * 30 + d) * 180 + cout];
        Wp[i] = (bf16_t)v;
    }
    // relative-position bias (pre-multiplied by log2e) in S^T-fragment layout
    for (int i = t; i < 6 * 9 * 9 * 64; i += stride) {
        int lane = i & 63;
        int f = i >> 6;               // [h][wv][nt]
        int nt = f % 9, wvq = (f / 9) % 9, h = f / 81;
        int q = wvq * 16 + (lane & 15);
        int qi = q / 12, qj = q % 12;
        #pragma unroll
        for (int r = 0; r < 4; ++r) {
            int k = nt * 16 + (lane >> 4) * 4 + r;
            int ki = k / 12, kj = k % 12;
            int rel = (qi - ki + 11) * 23 + (qj - kj + 11);
            BIASf[i * 4 + r] = (bf16_t)(bt[rel * 6 + h] * L2E);
        }
    }
    for (int i = t; i < 576; i += stride) {
        int c = i % 96, h = i / 96;
        int sec = c >> 5, d = c & 31;
        float v = 0.f;
        if (d < 30) {
            if (sec == 0)      v = bq[h * 30 + d] * qscale;
            else if (sec == 1) v = bk[h * 30 + d];
            else               v = bv[h * 30 + d];
        }
        bqkv[i] = v;
    }
}

// ---------------- fused attention kernel ----------------
// block = 576 threads = 9 waves; wave w owns M-strip rows [16w, 16w+16)
// LDS map (78336 B):
//   strips @ 0     : 9 x 4608 B (P chunks kt0..3 [16q][32tok] swizzled + tail 512B;
//                    Q/O transposes reuse chunk0 at distinct times; never clobbered)
//   K[2]   @ 41472 : [144][32] bf16 stride 64, swizzle byte^=((row&6)<<3), parity dbuf
//   Vt[2]  @ 59904 : [32 d][144 tok] bf16 stride 288; 64B-blocks 0..3 swizzled, parity dbuf
// W B-fragments come straight from global (L2/L3-resident, coalesced dwordx4).
// One barrier per head (after K/Vt scatter); epilogue barrier-free.
__global__ __launch_bounds__(576, 2)
void attn_kernel(const float* __restrict__ gs,
                 const bf16_t* __restrict__ Wqkv, const bf16_t* __restrict__ Wp,
                 const bf16_t* __restrict__ BIASf, const float* __restrict__ bqkv,
                 const float* __restrict__ bp, float* __restrict__ out)
{
    __shared__ __align__(16) unsigned char smem[78336];

    const int tid = threadIdx.x;
    const int lane = tid & 63;
    const int wv = tid >> 6;          // wave id = M-strip 0..8
    const int l15 = lane & 15;
    const int lg = lane >> 4;         // 0..3
    const int win = blockIdx.x;
    const float* __restrict__ gsw = gs + (size_t)win * 25920;

    constexpr int ST_BASE = 0;
    constexpr int K_BASE  = 41472;    // + (h&1)*9216
    constexpr int VT_BASE = 59904;    // + (h&1)*9216

    // ---- gs A-fragments into registers: row = 16*wv + l15, k-tile kt ----
    bf16x8 xa[6];
    {
        const int row = wv * 16 + l15;
        const float4* __restrict__ g4 = (const float4*)(gsw + row * 180);
        #pragma unroll
        for (int kt = 0; kt < 6; ++kt) {
            const int c0 = kt * 32 + lg * 8;
            float4 lo = {0.f, 0.f, 0.f, 0.f}, hi = {0.f, 0.f, 0.f, 0.f};
            if (c0 + 4 <= 180) lo = g4[c0 >> 2];
            if (c0 + 8 <= 180) hi = g4[(c0 >> 2) + 1];
            bf16x8 v;
            v[0] = (bf16_t)lo.x; v[1] = (bf16_t)lo.y; v[2] = (bf16_t)lo.z; v[3] = (bf16_t)lo.w;
            v[4] = (bf16_t)hi.x; v[5] = (bf16_t)hi.y; v[6] = (bf16_t)hi.z; v[7] = (bf16_t)hi.w;
            xa[kt] = v;
        }
    }

    bf16x8 ao[6];                     // per-head O A-fragments (persistent)
    char* const pb = (char*)smem + ST_BASE + wv * 4608;   // wave-private strip
    const int pswz = (l15 & 6) << 3;

    #pragma unroll
    for (int h = 0; h < 6; ++h) {
        const int KB = K_BASE + (h & 1) * 9216;
        const int VB = VT_BASE + (h & 1) * 9216;

        // ---- QKV GEMM: acc[nt] = X(strip) @ W[:, nt]; B-frags from L2 ----
        const bf16_t* __restrict__ wsrc = Wqkv + h * 18432;
        f32x4 acc[6];
        #pragma unroll
        for (int nt = 0; nt < 6; ++nt) acc[nt] = fzero4();
        __builtin_amdgcn_s_setprio(1);
        #pragma unroll
        for (int kt = 0; kt < 6; ++kt) {
            #pragma unroll
            for (int nt = 0; nt < 6; ++nt) {
                bf16x8 bw = *(const bf16x8*)(wsrc + (size_t)((kt * 6 + nt) * 64 + lane) * 8);
                acc[nt] = MFMA16(xa[kt], bw, acc[nt]);
            }
        }
        __builtin_amdgcn_s_setprio(0);

        // ---- scatter K,V to LDS (parity buffers); Q stays in registers ----
        bf16_t q8[8];
        {
            const int row0 = wv * 16 + lg * 4;
            // Q: nt 0,1 -> registers
            #pragma unroll
            for (int nt = 0; nt < 2; ++nt) {
                const float bias = bqkv[h * 96 + nt * 16 + l15];
                #pragma unroll
                for (int r = 0; r < 4; ++r)
                    q8[nt * 4 + r] = (bf16_t)(acc[nt][r] + bias);
            }
            // K: nt 2,3 -> row-major swizzled (4x b16)
            #pragma unroll
            for (int nt = 2; nt < 4; ++nt) {
                const float bias = bqkv[h * 96 + nt * 16 + l15];
                const int d32 = ((nt & 1) << 4) + l15;
                #pragma unroll
                for (int r = 0; r < 4; ++r) {
                    const int rr = row0 + r;
                    *(bf16_t*)(smem + KB + rr * 64 + ((d32 * 2) ^ ((rr & 6) << 3))) =
                        (bf16_t)(acc[nt][r] + bias);
                }
            }
            // V: nt 4,5 -> transposed, packed b64 (4 consecutive tokens)
            #pragma unroll
            for (int nt = 4; nt < 6; ++nt) {
                const float bias = bqkv[h * 96 + nt * 16 + l15];
                const int d32 = ((nt & 1) << 4) + l15;
                const int vswz = (wv < 8) ? (((d32 >> 2) & 3) << 4) : 0;
                bf16x4 vvv;
                #pragma unroll
                for (int r = 0; r < 4; ++r)
                    vvv[r] = (bf16_t)(acc[nt][r] + bias);
                *(bf16x4*)(smem + VB + d32 * 288 + ((row0 * 2) ^ vswz)) = vvv;
            }
        }
        __syncthreads();              // K/Vt(h) visible to all waves

        // ---- Q transpose through own strip chunk0 -> B-fragment aq ----
        #pragma unroll
        for (int r = 0; r < 4; ++r) {
            const int row = lg * 4 + r;
            const int swz = (row & 6) << 3;
            *(bf16_t*)(pb + row * 64 + ((l15 * 2) ^ swz))      = q8[r];
            *(bf16_t*)(pb + row * 64 + ((l15 * 2 + 32) ^ swz)) = q8[4 + r];
        }
        asm volatile("" ::: "memory");
        bf16x8 aq = *(const bf16x8*)(pb + l15 * 64 + ((lg * 16) ^ ((l15 & 6) << 3)));
        asm volatile("" ::: "memory");

        // ---- streaming S^T -> exp2 -> P (no max; S~N(0,1); log2e pre-folded) ----
        float sum = 0.f;
        #pragma unroll
        for (int nt = 0; nt < 9; ++nt) {
            const int krow = nt * 16 + l15;
            bf16x8 kf = *(const bf16x8*)(smem + KB + krow * 64 +
                                         ((lg * 16) ^ ((krow & 6) << 3)));
            f32x4 sv = MFMA16(kf, aq, fzero4());
            bf16x4 b4 = *(const bf16x4*)(BIASf +
                        (size_t)((((h * 9 + wv) * 9 + nt) * 64 + lane) * 4));
            bf16x4 pw;
            #pragma unroll
            for (int r = 0; r < 4; ++r) {
                float p = exp2f(sv[r] + (float)b4[r]);
                sum += p;
                pw[r] = (bf16_t)p;
            }
            if (nt < 8)
                *(bf16x4*)(pb + (nt >> 1) * 1024 + l15 * 64 +
                           ((((nt & 1) << 5) + lg * 8) ^ pswz)) = pw;
            else
                *(bf16x4*)(pb + 4096 + l15 * 32 + lg * 8) = pw;
        }
        sum += __shfl_xor(sum, 16, 64);
        sum += __shfl_xor(sum, 32, 64);
        const float rinv = 1.f / sum;  // normalization deferred to O epilogue
        asm volatile("" ::: "memory");

        // ---- PV: O(strip)[16x32] = P[16x144] @ Vt^T (tail predicated) ----
        f32x4 o0 = fzero4(), o1 = fzero4();
        __builtin_amdgcn_s_setprio(1);
        #pragma unroll
        for (int kt = 0; kt < 4; ++kt) {
            const int vs0 = ((l15 >> 2) & 3) << 4;
            bf16x8 ap  = *(const bf16x8*)(pb + kt * 1024 + l15 * 64 + ((lg * 16) ^ pswz));
            bf16x8 bv0 = *(const bf16x8*)(smem + VB + l15 * 288 + kt * 64 + ((lg * 16) ^ vs0));
            bf16x8 bv1 = *(const bf16x8*)(smem + VB + (16 + l15) * 288 + kt * 64 + ((lg * 16) ^ vs0));
            o0 = MFMA16(ap, bv0, o0);
            o1 = MFMA16(ap, bv1, o1);
        }
        {   // tail: tokens 128..143 (lg 0,1 read; lg 2,3 contribute zeros)
            bf16x8 ap  = bzero8();
            bf16x8 bv0 = bzero8();
            bf16x8 bv1 = bzero8();
            if (lg < 2) {
                ap  = *(const bf16x8*)(pb + 4096 + l15 * 32 + lg * 16);
                bv0 = *(const bf16x8*)(smem + VB + l15 * 288 + 256 + lg * 16);
                bv1 = *(const bf16x8*)(smem + VB + (16 + l15) * 288 + 256 + lg * 16);
            }
            o0 = MFMA16(ap, bv0, o0);
            o1 = MFMA16(ap, bv1, o1);
        }
        __builtin_amdgcn_s_setprio(0);

        // ---- normalize + transpose 16x32 O slice through chunk0 -> ao[h] ----
        asm volatile("" ::: "memory");
        #pragma unroll
        for (int r = 0; r < 4; ++r) {
            const float rq = __shfl(rinv, lg * 4 + r, 16);
            const int row = lg * 4 + r;
            const int swz = (row & 6) << 3;
            *(bf16_t*)(pb + row * 64 + ((l15 * 2) ^ swz))      = (bf16_t)(o0[r] * rq);
            *(bf16_t*)(pb + row * 64 + ((l15 * 2 + 32) ^ swz)) = (bf16_t)(o1[r] * rq);
        }
        asm volatile("" ::: "memory");
        ao[h] = *(const bf16x8*)(pb + l15 * 64 + ((lg * 16) ^ ((l15 & 6) << 3)));
        // no second barrier: next head writes the other K/Vt parity buffer, and
        // a wave can only reach the +2-head scatter after the next barrier.
    }

    // ---- output projection (barrier-free): out = O @ Wp + bp, W from L2 ----
    float* __restrict__ og = out + (size_t)win * 25920;
    #pragma unroll
    for (int half = 0; half < 2; ++half) {
        f32x4 accp[6];
        #pragma unroll
        for (int nt = 0; nt < 6; ++nt) accp[nt] = fzero4();
        __builtin_amdgcn_s_setprio(1);
        #pragma unroll
        for (int kt = 0; kt < 6; ++kt) {
            #pragma unroll
            for (int nt = 0; nt < 6; ++nt) {
                bf16x8 bw = *(const bf16x8*)(Wp +
                            (size_t)(((half * 6 + kt) * 6 + nt) * 64 + lane) * 8);
                accp[nt] = MFMA16(ao[kt], bw, accp[nt]);
            }
        }
        __builtin_amdgcn_s_setprio(0);
        #pragma unroll
        for (int nt = 0; nt < 6; ++nt) {
            const int col = half * 96 + nt * 16 + l15;
            if (col < 180) {
                const float bias = bp[col];
                #pragma unroll
                for (int r = 0; r < 4; ++r) {
                    const int row = wv * 16 + lg * 4 + r;
                    og[row * 180 + col] = accp[nt][r] + bias;
                }
            }
        }
    }
}

extern "C" void kernel_launch(void* const* d_in, const int* in_sizes, int n_in,
                              void* d_out, int out_size, void* d_ws, size_t ws_size,
                              hipStream_t stream) {
    const float* gs = (const float*)d_in[0];
    const float* wq = (const float*)d_in[1];
    const float* bq = (const float*)d_in[2];
    const float* wk = (const float*)d_in[3];
    const float* bk = (const float*)d_in[4];
    const float* wv = (const float*)d_in[5];
    const float* bv = (const float*)d_in[6];
    const float* wp = (const float*)d_in[7];
    const float* bp = (const float*)d_in[8];
    const float* bt = (const float*)d_in[9];

    char* ws = (char*)d_ws;
    bf16_t* Wqkv  = (bf16_t*)(ws);
    bf16_t* Wp    = (bf16_t*)(ws + 221184);
    bf16_t* BIASf = (bf16_t*)(ws + 294912);
    float*  bqkv  = (float*)(ws + 543744);

    pack_kernel<<<256, 256, 0, stream>>>(wq, bq, wk, bk, wv, bv, wp, bt,
                                         Wqkv, Wp, BIASf, bqkv);
    attn_kernel<<<2048, 576, 0, stream>>>(gs, Wqkv, Wp, BIASf, bqkv, bp, (float*)d_out);
}

// Round 9
// 335.132 us; speedup vs baseline: 1.3054x; 1.3054x over previous
//
#include <hip/hip_runtime.h>

// GSSelfAttn: B=2048 windows, N=144 tokens, D=180, H=6 heads, hd=30.
// R9: cross-head software pipeline. Per iteration h (ONE barrier):
//   Qtr(h) | QKV-GEMM(h+1) (indep MFMA stream) | S-loop(h) | scatter(h+1,
//   opposite parity K/Vt) | PV(h) | stage W(h+2) | Otr(h) | BAR.
// W staged in LDS (R7-style dbuf, R8's L2-direct reverted), V scatter packed
// b64, K/Vt parity dbuf, barrier-free epilogue (Wp halves pre-staged at h=4/5).
// LDS 152064 B: WB0 36864 | WB1 36864 | strips 41472 | K[2] 18432 | Vt[2] 18432.

typedef __bf16 bf16_t;
typedef __bf16 bf16x8 __attribute__((ext_vector_type(8)));
typedef __bf16 bf16x4 __attribute__((ext_vector_type(4)));
typedef float f32x4 __attribute__((ext_vector_type(4)));

#define MFMA16(a, b, c) __builtin_amdgcn_mfma_f32_16x16x32_bf16((a), (b), (c), 0, 0, 0)

static __device__ __forceinline__ f32x4 fzero4() {
    f32x4 z; z[0] = 0.f; z[1] = 0.f; z[2] = 0.f; z[3] = 0.f; return z;
}
static __device__ __forceinline__ bf16x8 bzero8() {
    bf16x8 z;
    #pragma unroll
    for (int i = 0; i < 8; ++i) z[i] = (bf16_t)0.f;
    return z;
}

// ---------------- pack kernel ----------------
// ws layout (bytes):
//   Wqkv  @ 0      : [h][kt6][nt6][lane64][j8] bf16      = 221184 B  (Q cols pre-scaled by 30^-.5*log2e)
//   Wp    @ 221184 : [half2][kt6][ntl6][lane64][j8] bf16 =  73728 B  (half-major)
//   BIASf @ 294912 : [h][wv9][nt9][lane64][r4] bf16      = 248832 B  (S^T fragment layout, *log2e)
//   bqkv  @ 543744 : [h][c96]                 fp32       =   2304 B  (Q part *scale*log2e)
__global__ void pack_kernel(const float* __restrict__ wq, const float* __restrict__ bq,
                            const float* __restrict__ wk, const float* __restrict__ bk,
                            const float* __restrict__ wv, const float* __restrict__ bv,
                            const float* __restrict__ wp, const float* __restrict__ bt,
                            bf16_t* __restrict__ Wqkv, bf16_t* __restrict__ Wp,
                            bf16_t* __restrict__ BIASf, float* __restrict__ bqkv)
{
    const int t = blockIdx.x * blockDim.x + threadIdx.x;
    const int stride = gridDim.x * blockDim.x;
    const float L2E = 1.4426950408889634f;
    const float qscale = 0.18257418583505536f * L2E;   // 30^-0.5 * log2e, folded into Q

    for (int i = t; i < 6 * 6 * 6 * 512; i += stride) {
        int j = i & 7, lane = (i >> 3) & 63;
        int f = i >> 9;               // [h][kt][nt]
        int nt = f % 6, kt = (f / 6) % 6, h = f / 36;
        int kin = kt * 32 + (lane >> 4) * 8 + j;
        int c = nt * 16 + (lane & 15);       // 0..95
        int sec = c >> 5, d = c & 31;
        float v = 0.f;
        if (kin < 180 && d < 30) {
            int col = h * 30 + d;
            if (sec == 0)      v = wq[kin * 180 + col] * qscale;
            else if (sec == 1) v = wk[kin * 180 + col];
            else               v = wv[kin * 180 + col];
        }
        Wqkv[i] = (bf16_t)v;
    }
    for (int i = t; i < 2 * 6 * 6 * 512; i += stride) {
        int j = i & 7, lane = (i >> 3) & 63;
        int f = i >> 9;               // [half][kt][ntl]
        int ntl = f % 6, kt = (f / 6) % 6, half = f / 36;
        int nt = half * 6 + ntl;
        int kin = kt * 32 + (lane >> 4) * 8 + j;
        int hh = kin >> 5, d = kin & 31;
        int cout = nt * 16 + (lane & 15);
        float v = 0.f;
        if (d < 30 && cout < 180) v = wp[(hh * 30 + d) * 180 + cout];
        Wp[i] = (bf16_t)v;
    }
    // relative-position bias (pre-multiplied by log2e) in S^T-fragment layout
    for (int i = t; i < 6 * 9 * 9 * 64; i += stride) {
        int lane = i & 63;
        int f = i >> 6;               // [h][wv][nt]
        int nt = f % 9, wvq = (f / 9) % 9, h = f / 81;
        int q = wvq * 16 + (lane & 15);
        int qi = q / 12, qj = q % 12;
        #pragma unroll
        for (int r = 0; r < 4; ++r) {
            int k = nt * 16 + (lane >> 4) * 4 + r;
            int ki = k / 12, kj = k % 12;
            int rel = (qi - ki + 11) * 23 + (qj - kj + 11);
            BIASf[i * 4 + r] = (bf16_t)(bt[rel * 6 + h] * L2E);
        }
    }
    for (int i = t; i < 576; i += stride) {
        int c = i % 96, h = i / 96;
        int sec = c >> 5, d = c & 31;
        float v = 0.f;
        if (d < 30) {
            if (sec == 0)      v = bq[h * 30 + d] * qscale;
            else if (sec == 1) v = bk[h * 30 + d];
            else               v = bv[h * 30 + d];
        }
        bqkv[i] = v;
    }
}

// ---------------- fused attention kernel ----------------
// block = 576 threads = 9 waves; wave w owns M-strip rows [16w, 16w+16)
// LDS map (152064 B):
//   WB[0] @ 0      : 36864 B (QKV head weights dbuf; Wp halves reuse at h=4/5)
//   WB[1] @ 36864  : 36864 B
//   strips@ 73728  : 9 x 4608 B (P chunks kt0..3 [16q][32tok] swizzled + 512B tail;
//                    Q/O transposes reuse chunk0 at distinct times)
//   K[2]  @ 115200 : [144][32] bf16 stride 64, swizzle ^((row&6)<<3), parity dbuf
//   Vt[2] @ 133632 : [32 d][144 tok] bf16 stride 288, blocks0..3 swizzled, parity dbuf
__global__ __launch_bounds__(576, 2)
void attn_kernel(const float* __restrict__ gs,
                 const bf16_t* __restrict__ Wqkv, const bf16_t* __restrict__ Wp,
                 const bf16_t* __restrict__ BIASf, const float* __restrict__ bqkv,
                 const float* __restrict__ bp, float* __restrict__ out)
{
    __shared__ __align__(16) unsigned char smem[152064];

    const int tid = threadIdx.x;
    const int lane = tid & 63;
    const int wv = tid >> 6;          // wave id = M-strip 0..8
    const int l15 = lane & 15;
    const int lg = lane >> 4;         // 0..3
    const int win = blockIdx.x;
    const float* __restrict__ gsw = gs + (size_t)win * 25920;

    constexpr int WB0     = 0;
    constexpr int WB1     = 36864;
    constexpr int ST_BASE = 73728;
    constexpr int K_BASE  = 115200;   // + parity*9216
    constexpr int VT_BASE = 133632;   // + parity*9216

    // ---- prologue: issue W(0),W(1) loads; load gs; stage both W buffers ----
    int4 wld0[4], wld1[4];
    #pragma unroll
    for (int i = 0; i < 4; ++i) {
        wld0[i] = *(const int4*)((const char*)Wqkv + (tid + i * 576) * 16);
        wld1[i] = *(const int4*)((const char*)Wqkv + 36864 + (tid + i * 576) * 16);
    }

    bf16x8 xa[6];
    {
        const int row = wv * 16 + l15;
        const float4* __restrict__ g4 = (const float4*)(gsw + row * 180);
        #pragma unroll
        for (int kt = 0; kt < 6; ++kt) {
            const int c0 = kt * 32 + lg * 8;
            float4 lo = {0.f, 0.f, 0.f, 0.f}, hi = {0.f, 0.f, 0.f, 0.f};
            if (c0 + 4 <= 180) lo = g4[c0 >> 2];
            if (c0 + 8 <= 180) hi = g4[(c0 >> 2) + 1];
            bf16x8 v;
            v[0] = (bf16_t)lo.x; v[1] = (bf16_t)lo.y; v[2] = (bf16_t)lo.z; v[3] = (bf16_t)lo.w;
            v[4] = (bf16_t)hi.x; v[5] = (bf16_t)hi.y; v[6] = (bf16_t)hi.z; v[7] = (bf16_t)hi.w;
            xa[kt] = v;
        }
    }
    #pragma unroll
    for (int i = 0; i < 4; ++i) {
        *(int4*)(smem + WB0 + (tid + i * 576) * 16) = wld0[i];
        *(int4*)(smem + WB1 + (tid + i * 576) * 16) = wld1[i];
    }
    __syncthreads();

    bf16x8 ao[6];                     // per-head O A-fragments (persistent)
    char* const pb = (char*)smem + ST_BASE + wv * 4608;   // wave-private strip
    const int pswz = (l15 & 6) << 3;
    const int row0 = wv * 16 + lg * 4;

    // QKV GEMM for head hh reading WB at wbofs; Q->q8o, K/Vt->parity(hh) LDS
    auto qkv_scatter = [&](const int hh, const int wbofs, bf16_t* q8o) {
        const int KB = K_BASE + (hh & 1) * 9216;
        const int VB = VT_BASE + (hh & 1) * 9216;
        f32x4 acc[6];
        #pragma unroll
        for (int nt = 0; nt < 6; ++nt) acc[nt] = fzero4();
        __builtin_amdgcn_s_setprio(1);
        #pragma unroll
        for (int kt = 0; kt < 6; ++kt) {
            #pragma unroll
            for (int nt = 0; nt < 6; ++nt) {
                bf16x8 bw = *(const bf16x8*)(smem + wbofs + ((kt * 6 + nt) * 64 + lane) * 16);
                acc[nt] = MFMA16(xa[kt], bw, acc[nt]);
            }
        }
        __builtin_amdgcn_s_setprio(0);
        // Q: nt 0,1 -> registers
        #pragma unroll
        for (int nt = 0; nt < 2; ++nt) {
            const float bias = bqkv[hh * 96 + nt * 16 + l15];
            #pragma unroll
            for (int r = 0; r < 4; ++r)
                q8o[nt * 4 + r] = (bf16_t)(acc[nt][r] + bias);
        }
        // K: nt 2,3 -> row-major swizzled
        #pragma unroll
        for (int nt = 2; nt < 4; ++nt) {
            const float bias = bqkv[hh * 96 + nt * 16 + l15];
            const int d32 = ((nt & 1) << 4) + l15;
            #pragma unroll
            for (int r = 0; r < 4; ++r) {
                const int rr = row0 + r;
                *(bf16_t*)(smem + KB + rr * 64 + ((d32 * 2) ^ ((rr & 6) << 3))) =
                    (bf16_t)(acc[nt][r] + bias);
            }
        }
        // V: nt 4,5 -> transposed, packed b64
        #pragma unroll
        for (int nt = 4; nt < 6; ++nt) {
            const float bias = bqkv[hh * 96 + nt * 16 + l15];
            const int d32 = ((nt & 1) << 4) + l15;
            const int vswz = (wv < 8) ? (((d32 >> 2) & 3) << 4) : 0;
            bf16x4 vvv;
            #pragma unroll
            for (int r = 0; r < 4; ++r)
                vvv[r] = (bf16_t)(acc[nt][r] + bias);
            *(bf16x4*)(smem + VB + d32 * 288 + ((row0 * 2) ^ vswz)) = vvv;
        }
    };

    bf16_t q8cur[8], q8nxt[8];
    qkv_scatter(0, WB0, q8cur);
    __syncthreads();                  // K/Vt(0) + WB staging visible

    #pragma unroll
    for (int h = 0; h < 6; ++h) {
        const int KB = K_BASE + (h & 1) * 9216;
        const int VB = VT_BASE + (h & 1) * 9216;
        const int WSTG = (h & 1) ? WB1 : WB0;   // staged this iter, read at h+2

        // ---- issue W(h+2)/Wp-half global loads ----
        int4 wn[4];
        {
            const char* __restrict__ nsrc = (h < 4)
                ? ((const char*)Wqkv + (h + 2) * 36864)
                : ((const char*)Wp + (h - 4) * 36864);
            #pragma unroll
            for (int i = 0; i < 4; ++i)
                wn[i] = *(const int4*)(nsrc + (tid + i * 576) * 16);
        }

        // ---- Q transpose (head h) through own strip chunk0 ----
        #pragma unroll
        for (int r = 0; r < 4; ++r) {
            const int row = lg * 4 + r;
            const int swz = (row & 6) << 3;
            *(bf16_t*)(pb + row * 64 + ((l15 * 2) ^ swz))      = q8cur[r];
            *(bf16_t*)(pb + row * 64 + ((l15 * 2 + 32) ^ swz)) = q8cur[4 + r];
        }
        asm volatile("" ::: "memory");

        // ---- QKV GEMM + scatter for head h+1 (independent stream) ----
        if (h < 5)
            qkv_scatter(h + 1, (h & 1) ? WB0 : WB1, q8nxt);

        // ---- aq read; streaming S^T -> exp2 -> P (head h) ----
        bf16x8 aq = *(const bf16x8*)(pb + l15 * 64 + ((lg * 16) ^ ((l15 & 6) << 3)));
        asm volatile("" ::: "memory");
        float sum = 0.f;
        #pragma unroll
        for (int nt = 0; nt < 9; ++nt) {
            const int krow = nt * 16 + l15;
            bf16x8 kf = *(const bf16x8*)(smem + KB + krow * 64 +
                                         ((lg * 16) ^ ((krow & 6) << 3)));
            f32x4 sv = MFMA16(kf, aq, fzero4());
            bf16x4 b4 = *(const bf16x4*)(BIASf +
                        (size_t)((((h * 9 + wv) * 9 + nt) * 64 + lane) * 4));
            bf16x4 pw;
            #pragma unroll
            for (int r = 0; r < 4; ++r) {
                float p = exp2f(sv[r] + (float)b4[r]);
                sum += p;
                pw[r] = (bf16_t)p;
            }
            if (nt < 8)
                *(bf16x4*)(pb + (nt >> 1) * 1024 + l15 * 64 +
                           ((((nt & 1) << 5) + lg * 8) ^ pswz)) = pw;
            else
                *(bf16x4*)(pb + 4096 + l15 * 32 + lg * 8) = pw;
        }
        sum += __shfl_xor(sum, 16, 64);
        sum += __shfl_xor(sum, 32, 64);
        const float rinv = 1.f / sum;  // normalization deferred to O epilogue
        asm volatile("" ::: "memory");

        // ---- PV: O(strip)[16x32] = P[16x144] @ Vt^T (tail predicated) ----
        f32x4 o0 = fzero4(), o1 = fzero4();
        __builtin_amdgcn_s_setprio(1);
        #pragma unroll
        for (int kt = 0; kt < 4; ++kt) {
            const int vs0 = ((l15 >> 2) & 3) << 4;
            bf16x8 ap  = *(const bf16x8*)(pb + kt * 1024 + l15 * 64 + ((lg * 16) ^ pswz));
            bf16x8 bv0 = *(const bf16x8*)(smem + VB + l15 * 288 + kt * 64 + ((lg * 16) ^ vs0));
            bf16x8 bv1 = *(const bf16x8*)(smem + VB + (16 + l15) * 288 + kt * 64 + ((lg * 16) ^ vs0));
            o0 = MFMA16(ap, bv0, o0);
            o1 = MFMA16(ap, bv1, o1);
        }
        {   // tail: tokens 128..143 (lg 0,1 read; lg 2,3 contribute zeros)
            bf16x8 ap  = bzero8();
            bf16x8 bv0 = bzero8();
            bf16x8 bv1 = bzero8();
            if (lg < 2) {
                ap  = *(const bf16x8*)(pb + 4096 + l15 * 32 + lg * 16);
                bv0 = *(const bf16x8*)(smem + VB + l15 * 288 + 256 + lg * 16);
                bv1 = *(const bf16x8*)(smem + VB + (16 + l15) * 288 + 256 + lg * 16);
            }
            o0 = MFMA16(ap, bv0, o0);
            o1 = MFMA16(ap, bv1, o1);
        }
        __builtin_amdgcn_s_setprio(0);

        // ---- stage W(h+2)/Wp-half into WSTG (last read at QKV(h), iter h-1) ----
        #pragma unroll
        for (int i = 0; i < 4; ++i)
            *(int4*)(smem + WSTG + (tid + i * 576) * 16) = wn[i];

        // ---- normalize + transpose 16x32 O slice through chunk0 -> ao[h] ----
        asm volatile("" ::: "memory");
        #pragma unroll
        for (int r = 0; r < 4; ++r) {
            const float rq = __shfl(rinv, lg * 4 + r, 16);
            const int row = lg * 4 + r;
            const int swz = (row & 6) << 3;
            *(bf16_t*)(pb + row * 64 + ((l15 * 2) ^ swz))      = (bf16_t)(o0[r] * rq);
            *(bf16_t*)(pb + row * 64 + ((l15 * 2 + 32) ^ swz)) = (bf16_t)(o1[r] * rq);
        }
        asm volatile("" ::: "memory");
        ao[h] = *(const bf16x8*)(pb + l15 * 64 + ((lg * 16) ^ ((l15 & 6) << 3)));

        __syncthreads();              // one barrier per head

        #pragma unroll
        for (int i = 0; i < 8; ++i) q8cur[i] = q8nxt[i];
    }

    // ---- output projection (barrier-free): WB0 = Wp half0, WB1 = Wp half1 ----
    float* __restrict__ og = out + (size_t)win * 25920;
    #pragma unroll
    for (int half = 0; half < 2; ++half) {
        const int WH = half ? WB1 : WB0;
        f32x4 accp[6];
        #pragma unroll
        for (int nt = 0; nt < 6; ++nt) accp[nt] = fzero4();
        __builtin_amdgcn_s_setprio(1);
        #pragma unroll
        for (int kt = 0; kt < 6; ++kt) {
            #pragma unroll
            for (int nt = 0; nt < 6; ++nt) {
                bf16x8 bw = *(const bf16x8*)(smem + WH + ((kt * 6 + nt) * 64 + lane) * 16);
                accp[nt] = MFMA16(ao[kt], bw, accp[nt]);
            }
        }
        __builtin_amdgcn_s_setprio(0);
        #pragma unroll
        for (int nt = 0; nt < 6; ++nt) {
            const int col = half * 96 + nt * 16 + l15;
            if (col < 180) {
                const float bias = bp[col];
                #pragma unroll
                for (int r = 0; r < 4; ++r) {
                    const int row = wv * 16 + lg * 4 + r;
                    og[row * 180 + col] = accp[nt][r] + bias;
                }
            }
        }
    }
}

extern "C" void kernel_launch(void* const* d_in, const int* in_sizes, int n_in,
                              void* d_out, int out_size, void* d_ws, size_t ws_size,
                              hipStream_t stream) {
    const float* gs = (const float*)d_in[0];
    const float* wq = (const float*)d_in[1];
    const float* bq = (const float*)d_in[2];
    const float* wk = (const float*)d_in[3];
    const float* bk = (const float*)d_in[4];
    const float* wv = (const float*)d_in[5];
    const float* bv = (const float*)d_in[6];
    const float* wp = (const float*)d_in[7];
    const float* bp = (const float*)d_in[8];
    const float* bt = (const float*)d_in[9];

    char* ws = (char*)d_ws;
    bf16_t* Wqkv  = (bf16_t*)(ws);
    bf16_t* Wp    = (bf16_t*)(ws + 221184);
    bf16_t* BIASf = (bf16_t*)(ws + 294912);
    float*  bqkv  = (float*)(ws + 543744);

    pack_kernel<<<256, 256, 0, stream>>>(wq, bq, wk, bk, wv, bv, wp, bt,
                                         Wqkv, Wp, BIASf, bqkv);
    attn_kernel<<<2048, 576, 0, stream>>>(gs, Wqkv, Wp, BIASf, bqkv, bp, (float*)d_out);
}